// Round 32
// baseline (238.544 us; speedup 1.0000x reference)
//
#include <hip/hip_runtime.h>
#include <hip/hip_bf16.h>
#include <math.h>

#define N 4096
#define IN_FT 512
#define OUT_FT 512
#define COS_THR 0.5f
#define COS_K 10
#define EPSN 1e-12f
#define CAP 256          // max stored nnz per row/col (actual ~10)
#define NW (N / 32)      // bitmask words per row
#define CAP_C 128        // window candidate slots (exact-fix path)
#define GAPWIN 1e-2f     // >= 2*delta'; bf16x1 delta 4e-3 + pack trunc 5e-4
#define CNB 32           // 128-blocks per side
#define T0 0.08f         // candidate threshold (guards make this safe)
#define SLOTS 24         // slots per (row, 128-col cell); P(overflow)~4e-6 total
#define NSLOT (32 * SLOTS)   // 768 slots per row = 12 per lane

typedef short s16x8 __attribute__((ext_vector_type(8)));
typedef float f32x4 __attribute__((ext_vector_type(4)));

__device__ __forceinline__ unsigned short f2bf(float f) {
    unsigned u = __float_as_uint(f);
    u += 0x7fff + ((u >> 16) & 1);          // RNE to bf16
    return (unsigned short)(u >> 16);
}
__device__ __forceinline__ float bf2f(unsigned short h) {
    return __uint_as_float(((unsigned)h) << 16);
}
__device__ __forceinline__ void gload_lds16(const void* g, void* l) {
    __builtin_amdgcn_global_load_lds(
        (const __attribute__((address_space(1))) void*)g,
        (__attribute__((address_space(3))) void*)l, 16, 0, 0);
}

// ---------- row-normalize: bf16 hi/lo of xn + norms; NaN-fill cpack row ----------
__global__ __launch_bounds__(256) void rownorm_k(const float* __restrict__ x,
                                                 unsigned short* __restrict__ xnh,
                                                 unsigned short* __restrict__ xnl,
                                                 float* __restrict__ norminv,
                                                 float* __restrict__ nrm,
                                                 int* __restrict__ fbflag,
                                                 unsigned* __restrict__ cpack) {
    int row = blockIdx.x;
    const float* xr = x + (size_t)row * IN_FT;
    // NaN-fill this row's packed slots (replaces the separate memset dispatch)
#pragma unroll
    for (int q = 0; q < 3; ++q)
        cpack[(size_t)row * NSLOT + threadIdx.x + q * 256] = 0xFFFFFFFFu;
    float s = 0.f;
    for (int j = threadIdx.x; j < IN_FT; j += 256) { float v = xr[j]; s += v * v; }
    __shared__ float red[256];
    red[threadIdx.x] = s; __syncthreads();
    for (int off = 128; off > 0; off >>= 1) {
        if (threadIdx.x < off) red[threadIdx.x] += red[threadIdx.x + off];
        __syncthreads();
    }
    float nr = fmaxf(sqrtf(red[0]), 1e-12f);
    float inv = 1.0f / nr;
    if (threadIdx.x == 0) { norminv[row] = inv; nrm[row] = nr; fbflag[row] = 0; }
    for (int j = threadIdx.x; j < IN_FT; j += 256) {
        float v = xr[j] * inv;                 // same op the exact paths replay
        unsigned short hi = f2bf(v);
        unsigned short lo = f2bf(v - bf2f(hi));
        xnh[(size_t)row * IN_FT + j] = hi;
        xnl[(size_t)row * IN_FT + j] = lo;
    }
}

// ---------- approx cos: bf16x1 MFMA, upper-tri + mirror; PACKED slot emission ----------
__global__ __launch_bounds__(256) void cos_gemm_k(const unsigned short* __restrict__ xh,
                                                  unsigned* __restrict__ cpack,
                                                  int* __restrict__ ccntg) {
    __shared__ __align__(16) unsigned short As[2][128 * 32];
    __shared__ __align__(16) unsigned short Bs[2][128 * 32];
    __shared__ int cntU[128], cntM[128];
    int bid = blockIdx.x;                      // 0 .. 527
    int t = (bid & 7) * 66 + (bid >> 3);       // XCD-chunked bijection
    int by = 0;
    while (t >= CNB - by) { t -= CNB - by; ++by; }
    int bx = by + t;                           // by <= bx
    int tid = threadIdx.x;
    int wave = tid >> 6, l = tid & 63;
    int bi = by * 128, bj = bx * 128;
    int wm = wave >> 1, wn = wave & 1;
    int lm0 = wm * 64, ln0 = wn * 64;
    int lr4 = l >> 2;
    int lc4s = (((l & 3) ^ ((l >> 3) & 3)) * 8);   // swizzled SOURCE chunk
    int lr = l & 15, lg = l >> 4;
    int kqs = (((l >> 4) ^ ((l >> 1) & 3)) * 8);   // swizzled read chunk
    f32x4 acc[4][4] = {};
    int buf = 0;
#pragma unroll
    for (int q = 0; q < 2; ++q) {
        int r0 = (wave + q * 4) * 16;
        gload_lds16(xh + (size_t)(bi + r0 + lr4) * IN_FT + lc4s, &As[0][r0 * 32]);
        gload_lds16(xh + (size_t)(bj + r0 + lr4) * IN_FT + lc4s, &Bs[0][r0 * 32]);
    }
    asm volatile("s_waitcnt vmcnt(0)" ::: "memory");
    __syncthreads();
    for (int kt = 0; kt < 16; ++kt) {
        if (kt + 1 < 16) {
            int kc = (kt + 1) * 32;
#pragma unroll
            for (int q = 0; q < 2; ++q) {
                int r0 = (wave + q * 4) * 16;
                gload_lds16(xh + (size_t)(bi + r0 + lr4) * IN_FT + kc + lc4s,
                            &As[buf ^ 1][r0 * 32]);
                gload_lds16(xh + (size_t)(bj + r0 + lr4) * IN_FT + kc + lc4s,
                            &Bs[buf ^ 1][r0 * 32]);
            }
        }
        s16x8 a[4], b[4];
#pragma unroll
        for (int mi = 0; mi < 4; ++mi)
            a[mi] = *(const s16x8*)&As[buf][(lm0 + mi * 16 + lr) * 32 + kqs];
#pragma unroll
        for (int ni = 0; ni < 4; ++ni)
            b[ni] = *(const s16x8*)&Bs[buf][(ln0 + ni * 16 + lr) * 32 + kqs];
#pragma unroll
        for (int mi = 0; mi < 4; ++mi)
#pragma unroll
            for (int ni = 0; ni < 4; ++ni)
                acc[mi][ni] = __builtin_amdgcn_mfma_f32_16x16x32_bf16(a[mi], b[ni], acc[mi][ni], 0, 0, 0);
        asm volatile("s_waitcnt vmcnt(0)" ::: "memory");
        __syncthreads();
        buf ^= 1;
    }
    // ---- packed slot emission epilogue ----
    if (tid < 128) { cntU[tid] = 0; cntM[tid] = 0; }
    __syncthreads();
#pragma unroll
    for (int mi = 0; mi < 4; ++mi)
#pragma unroll
        for (int r = 0; r < 4; ++r) {
            int rl = lm0 + mi * 16 + lg * 4 + r;
#pragma unroll
            for (int ni = 0; ni < 4; ++ni) {
                float val = acc[mi][ni][r];
                if (val > T0) {
                    int p = atomicAdd(&cntU[rl], 1);
                    if (p < SLOTS) {
                        int n = bj + ln0 + ni * 16 + lr;
                        size_t base = ((size_t)(bi + rl) * 32 + bx) * SLOTS + p;
                        cpack[base] = (__float_as_uint(val) & 0xFFFFF000u) | (unsigned)n;
                    }
                }
            }
        }
    if (bx != by) {
#pragma unroll
        for (int ni = 0; ni < 4; ++ni) {
            int rl2 = ln0 + ni * 16 + lr;
#pragma unroll
            for (int mi = 0; mi < 4; ++mi)
#pragma unroll
                for (int r = 0; r < 4; ++r) {
                    float val = acc[mi][ni][r];
                    if (val > T0) {
                        int p = atomicAdd(&cntM[rl2], 1);
                        if (p < SLOTS) {
                            int col = bi + lm0 + mi * 16 + lg * 4 + r;
                            size_t base = ((size_t)(bj + rl2) * 32 + by) * SLOTS + p;
                            cpack[base] = (__float_as_uint(val) & 0xFFFFF000u) | (unsigned)col;
                        }
                    }
                }
        }
    }
    __syncthreads();
    if (tid < 128) {
        ccntg[(size_t)(bi + tid) * 32 + bx] = cntU[tid];
        if (bx != by) ccntg[(size_t)(bj + tid) * 32 + by] = cntM[tid];
    }
}

// ---------- top-k: 2 rows/block, 2 co-op waves per row ----------
// Wave A (wsub==0) runs the unchanged r29 front-end; BOTH waves split the
// exact-fix gather passes (A: members mb%8<4, B: mb%8>=4) with the verbatim
// r29 per-member segment partition + xor tree -> exv bit-identical. Wave A
// finishes rank/flags/mask/lists. Barriers are unconditional (skip flags
// instead of early returns) -> no barrier divergence. 8192 waves total
// (vs 4096) -> 100% occupancy cap; fix passes 5 -> 3.
__global__ __launch_bounds__(256) void topk_fast_k(const unsigned* __restrict__ cpack,
                                                   const int* __restrict__ ccntg,
                                                   const float* __restrict__ x,
                                                   const float* __restrict__ norminv,
                                                   unsigned* __restrict__ maskT,
                                                   const float* __restrict__ w2,
                                                   const float* __restrict__ Hmat,
                                                   int* __restrict__ rlist,
                                                   float* __restrict__ rval,
                                                   int* __restrict__ rcnt,
                                                   int* __restrict__ fbflag) {
    int tid = threadIdx.x;
    int wid2 = tid >> 7;                       // row within block (0/1)
    int wsub = (tid >> 6) & 1;                 // wave within the row pair
    int lane = tid & 63;
    int row = blockIdx.x * 2 + wid2;
    __shared__ int   cjj_s[2][CAP_C];
    __shared__ float exv_s[2][CAP_C];
    __shared__ unsigned char selw_s[2][CAP_C];
    __shared__ unsigned lmask_s[2][NW];
    __shared__ float xs_s[2][IN_FT];
    __shared__ int   Mw_s[2];
    __shared__ int   dofix_s[2];
    int*            cjj  = cjj_s[wid2];
    float*          exv  = exv_s[wid2];
    unsigned char*  selw = selw_s[wid2];
    unsigned*       lmask = lmask_s[wid2];
    float*          xs   = xs_s[wid2];
    // --- both waves stage their half of the x row (needed on the common fix path) ---
    {
        const float4* xr4 = (const float4*)(x + (size_t)row * IN_FT);
        ((float4*)xs)[lane + wsub * 64] = xr4[lane + wsub * 64];
    }
    // --- front-end state (wave A only; survives the barriers) ---
    float cv[12]; int ci[12];
    unsigned char flag[12];
    int mypos[12];
    int Mw = 0;
    bool okr = false, fixr = false;
    if (wsub == 0) {
        // guards from cell counts (shfl reduce)
        int cc = (lane < 32) ? ccntg[(size_t)row * 32 + lane] : 0;
        int sum = cc, mx = cc;
#pragma unroll
        for (int off = 32; off > 0; off >>= 1) {
            sum += __shfl_xor(sum, off);
            int m2 = __shfl_xor(mx, off);
            mx = m2 > mx ? m2 : mx;
        }
        if (!(mx > SLOTS || sum < COS_K)) {
            // load 12 packed slots/lane (coalesced; NaN -> inert)
            const unsigned* cpr = cpack + (size_t)row * NSLOT;
#pragma unroll
            for (int i = 0; i < 12; ++i) {
                unsigned u = cpr[lane + i * 64];
                float v = __uint_as_float(u & 0xFFFFF000u);
                bool ok = (v == v);
                cv[i] = ok ? v : -INFINITY;
                ci[i] = ok ? (int)(u & 0xFFFu) : 0x7fffffff;
            }
            // top-10 on approx, (value desc, index asc); win uniform
            int winr[10];
            float v10 = 0.f;
            unsigned exm = 0;
            for (int t = 0; t < COS_K; ++t) {
                float best = -INFINITY; int bidx = 0x7fffffff;
#pragma unroll
                for (int i = 0; i < 12; ++i)
                    if (!((exm >> i) & 1) &&
                        (cv[i] > best || (cv[i] == best && ci[i] < bidx))) { best = cv[i]; bidx = ci[i]; }
#pragma unroll
                for (int off = 32; off > 0; off >>= 1) {
                    float v2 = __shfl_xor(best, off);
                    int   i2 = __shfl_xor(bidx, off);
                    if (v2 > best || (v2 == best && i2 < bidx)) { best = v2; bidx = i2; }
                }
#pragma unroll
                for (int i = 0; i < 12; ++i)        // j unique -> owner marks
                    if (ci[i] == bidx) exm |= 1u << i;
                winr[t] = bidx;                     // wave-uniform
                if (t == COS_K - 1) v10 = best;
            }
            if (v10 - GAPWIN > T0) {
                // window membership + provisional flags
                unsigned iswm = 0; int wc = 0;
#pragma unroll
                for (int i = 0; i < 12; ++i) {
                    bool w = (cv[i] > v10 - GAPWIN) || (fabsf(cv[i] - COS_THR) < GAPWIN);
                    if (w) { iswm |= 1u << i; ++wc; }
                    bool iw = false;
#pragma unroll
                    for (int t = 0; t < COS_K; ++t) iw |= (winr[t] == ci[i]);
                    flag[i] = (cv[i] > COS_THR || iw) ? 1 : 0;
                }
                int scan = wc;
#pragma unroll
                for (int off = 1; off < 64; off <<= 1) {
                    int nv = __shfl_up(scan, off);
                    if (lane >= off) scan += nv;
                }
                Mw = __shfl(scan, 63);
                if (Mw <= CAP_C) {
                    okr = true;
                    if (Mw > COS_K) {
                        fixr = true;
                        int pos = scan - wc;
#pragma unroll
                        for (int i = 0; i < 12; ++i) {
                            if ((iswm >> i) & 1) { cjj[pos] = ci[i]; mypos[i] = pos; ++pos; }
                            else mypos[i] = -1;
                        }
                    }
                }
            }
        }
        if (lane == 0) {
            dofix_s[wid2] = fixr ? 1 : 0;
            Mw_s[wid2] = Mw;
            if (!okr) fbflag[row] = 1;
        }
    }
    __syncthreads();                           // barrier A (unconditional)
    // --- exact fix gathers: BOTH waves, interleaved member blocks ---
    if (dofix_s[wid2]) {
        int MwL = Mw_s[wid2];
        float invr = norminv[row];
        int grp = lane >> 4;                   // 0..3 member group
        int q = lane & 15;                     // k-segment within member
        for (int mb = wsub * 4; mb < MwL; mb += 8) {   // A: 0,8,..; B: 4,12,..
            int m = mb + grp;
            float part = 0.f;
            int j = (m < MwL) ? cjj[m] : cjj[0];
            float invj_ = norminv[j];
            const float4* xj4 = (const float4*)(x + (size_t)j * IN_FT);
            int kb = q * 32;
            float4 e0 = xj4[q * 8 + 0], e1 = xj4[q * 8 + 1];
            float4 e2 = xj4[q * 8 + 2], e3 = xj4[q * 8 + 3];
            float4 e4 = xj4[q * 8 + 4], e5 = xj4[q * 8 + 5];
            float4 e6 = xj4[q * 8 + 6], e7 = xj4[q * 8 + 7];
            const float4* f4s[8] = {&e0, &e1, &e2, &e3, &e4, &e5, &e6, &e7};
#pragma unroll
            for (int s = 0; s < 8; ++s) {
                float4 e = *f4s[s];
                part = fmaf(xs[kb + s * 4 + 0] * invr, e.x * invj_, part);
                part = fmaf(xs[kb + s * 4 + 1] * invr, e.y * invj_, part);
                part = fmaf(xs[kb + s * 4 + 2] * invr, e.z * invj_, part);
                part = fmaf(xs[kb + s * 4 + 3] * invr, e.w * invj_, part);
            }
#pragma unroll
            for (int off = 1; off < 16; off <<= 1)
                part += __shfl_xor(part, off);
            if (q == 0 && m < MwL) exv[m] = part;
        }
    }
    __syncthreads();                           // barrier B (unconditional)
    if (wsub != 0) return;                     // wave B done (no more barriers)
    if (!okr) return;                          // failed row: topk_fb overwrites
    if (fixr) {
        for (int w = lane; w < Mw; w += 64) {  // rank, identical comparator
            float vv = exv[w]; int j = cjj[w];
            int rank = 0;
            for (int m2 = 0; m2 < Mw; ++m2) {
                float v2 = exv[m2]; int j2 = cjj[m2];
                if (v2 > vv || (v2 == vv && j2 < j)) ++rank;
            }
            selw[w] = (rank < COS_K) ? 1 : 0;
        }
#pragma unroll
        for (int i = 0; i < 12; ++i)
            if (mypos[i] >= 0)
                flag[i] = ((exv[mypos[i]] > COS_THR) || selw[mypos[i]]) ? 1 : 0;
    }
    // --- build row bitmask (intra-wave LDS ops program-ordered) ---
    lmask[lane] = 0; lmask[lane + 64] = 0;
#pragma unroll
    for (int i = 0; i < 12; ++i)
        if (flag[i]) atomicOr(&lmask[ci[i] >> 5], 1u << (ci[i] & 31));
    unsigned w0 = lmask[lane], w1 = lmask[lane + 64];
    maskT[(size_t)lane * N + row] = w0;
    maskT[(size_t)(lane + 64) * N + row] = w1;
    // --- row list (ascending j) ---
    int c0 = __popc(w0), c1 = __popc(w1);
    int s0 = c0, s1 = c1;
#pragma unroll
    for (int off = 1; off < 64; off <<= 1) {
        int n0 = __shfl_up(s0, off);
        int n1 = __shfl_up(s1, off);
        if (lane >= off) { s0 += n0; s1 += n1; }
    }
    int tot0 = __shfl(s0, 63), tot1 = __shfl(s1, 63);
    int b0 = s0 - c0, b1 = tot0 + s1 - c1;
    {
        unsigned m = w0; int pos = b0;
        while (m) {
            int b = __builtin_ctz(m); m &= m - 1;
            int j = lane * 32 + b;
            if (pos < CAP) {
                size_t ofs = (size_t)row * N + j;
                rlist[(size_t)row * CAP + pos] = j;
                rval[(size_t)row * CAP + pos] = w2[ofs] * Hmat[ofs];
            }
            ++pos;
        }
        m = w1; pos = b1;
        while (m) {
            int b = __builtin_ctz(m); m &= m - 1;
            int j = (lane + 64) * 32 + b;
            if (pos < CAP) {
                size_t ofs = (size_t)row * N + j;
                rlist[(size_t)row * CAP + pos] = j;
                rval[(size_t)row * CAP + pos] = w2[ofs] * Hmat[ofs];
            }
            ++pos;
        }
    }
    if (lane == 0) {
        int tot = tot0 + tot1;
        rcnt[row] = tot < CAP ? tot : CAP;
    }
}

// ---------- fallback: EXACT row recompute + selection (guarded, rare) ----------
__global__ __launch_bounds__(256) void topk_fb_k(const int* __restrict__ fbflag,
                                                 const float* __restrict__ x,
                                                 const float* __restrict__ norminv,
                                                 unsigned* __restrict__ maskT,
                                                 const float* __restrict__ w2,
                                                 const float* __restrict__ Hmat,
                                                 int* __restrict__ rlist,
                                                 float* __restrict__ rval,
                                                 int* __restrict__ rcnt) {
    int row = blockIdx.x;
    if (!fbflag[row]) return;
    int tid = threadIdx.x;
    int lane = tid & 63, wid = tid >> 6;
    __shared__ float xrow[IN_FT];
    __shared__ float wv[4][10];
    __shared__ int   wi[4][10];
    __shared__ int   win[10];
    __shared__ int   wtot[4];
    const float* xr = x + (size_t)row * IN_FT;
    xrow[tid] = xr[tid]; xrow[tid + 256] = xr[tid + 256];
    __syncthreads();
    float invr = norminv[row];
    float v[16];
    const float4* xjp[16];
    float invj[16];
#pragma unroll
    for (int c = 0; c < 16; ++c) {
        int j = tid * 16 + c;
        xjp[c] = (const float4*)(x + (size_t)j * IN_FT);
        invj[c] = norminv[j];
        v[c] = 0.f;
    }
    for (int k4 = 0; k4 < IN_FT / 4; ++k4) {
        float xv0 = xrow[k4 * 4 + 0] * invr;
        float xv1 = xrow[k4 * 4 + 1] * invr;
        float xv2 = xrow[k4 * 4 + 2] * invr;
        float xv3 = xrow[k4 * 4 + 3] * invr;
#pragma unroll
        for (int c = 0; c < 16; ++c) {
            float4 e = xjp[c][k4];
            v[c] = fmaf(xv0, e.x * invj[c], v[c]);
            v[c] = fmaf(xv1, e.y * invj[c], v[c]);
            v[c] = fmaf(xv2, e.z * invj[c], v[c]);
            v[c] = fmaf(xv3, e.w * invj[c], v[c]);
        }
    }
    unsigned fl = 0;
#pragma unroll
    for (int c = 0; c < 16; ++c)
        if (v[c] > COS_THR) fl |= 1u << c;
    unsigned exm = 0;
#pragma unroll
    for (int t = 0; t < COS_K; ++t) {
        float best = -INFINITY; int bidx = 0x7fffffff;
#pragma unroll
        for (int c = 0; c < 16; ++c)
            if (!((exm >> c) & 1) && v[c] > best) { best = v[c]; bidx = tid * 16 + c; }
#pragma unroll
        for (int off = 32; off > 0; off >>= 1) {
            float v2 = __shfl_xor(best, off);
            int   i2 = __shfl_xor(bidx, off);
            if (v2 > best || (v2 == best && i2 < bidx)) { best = v2; bidx = i2; }
        }
        if ((bidx >> 4) == tid) exm |= 1u << (bidx & 15);
        if (lane == t) { wv[wid][t] = best; wi[wid][t] = bidx; }
    }
    __syncthreads();
    if (wid == 0) {
        float mv = -INFINITY; int mi = 0x7fffffff;
        if (lane < 40) { int g = lane / 10, s = lane - g * 10; mv = wv[g][s]; mi = wi[g][s]; }
        for (int t = 0; t < COS_K; ++t) {
            float best = mv; int bidx = mi;
#pragma unroll
            for (int off = 32; off > 0; off >>= 1) {
                float v2 = __shfl_xor(best, off);
                int   i2 = __shfl_xor(bidx, off);
                if (v2 > best || (v2 == best && i2 < bidx)) { best = v2; bidx = i2; }
            }
            if (mi == bidx) mv = -INFINITY;
            if (lane == 0) win[t] = bidx;
        }
    }
    __syncthreads();
#pragma unroll
    for (int t = 0; t < COS_K; ++t) {
        int wj = win[t];
        if ((wj >> 4) == tid) fl |= 1u << (wj & 15);
    }
    unsigned flp = __shfl_xor(fl, 1);
    if (!(tid & 1))
        maskT[(size_t)(tid >> 1) * N + row] = (fl & 0xffffu) | (flp << 16);
    int cnt = __popc(fl);
    int scan = cnt;
#pragma unroll
    for (int off = 1; off < 64; off <<= 1) {
        int nv = __shfl_up(scan, off);
        if (lane >= off) scan += nv;
    }
    if (lane == 63) wtot[wid] = scan;
    __syncthreads();
    int base = scan - cnt;
    for (int w = 0; w < wid; ++w) base += wtot[w];
    unsigned m = fl;
    int pos = base;
    while (m) {
        int c = __builtin_ctz(m); m &= m - 1;
        int j = tid * 16 + c;
        if (pos < CAP) {
            size_t ofs = (size_t)row * N + j;
            rlist[(size_t)row * CAP + pos] = j;
            rval[(size_t)row * CAP + pos] = w2[ofs] * Hmat[ofs];
        }
        ++pos;
    }
    if (tid == 0) {
        int tot = wtot[0] + wtot[1] + wtot[2] + wtot[3];
        rcnt[row] = tot < CAP ? tot : CAP;
    }
}

// ---------- split proj_w into bf16 (hi, lo) ----------
__global__ __launch_bounds__(256) void cast_w_k(const float* __restrict__ w,
                                                unsigned short* __restrict__ wh,
                                                unsigned short* __restrict__ wl) {
    int i4 = blockIdx.x * 256 + threadIdx.x;   // 65536 float4s
    float4 f = ((const float4*)w)[i4];
    ushort4 hi, lo;
    hi.x = f2bf(f.x); lo.x = f2bf(f.x - bf2f(hi.x));
    hi.y = f2bf(f.y); lo.y = f2bf(f.y - bf2f(hi.y));
    hi.z = f2bf(f.z); lo.z = f2bf(f.z - bf2f(hi.z));
    hi.w = f2bf(f.w); lo.w = f2bf(f.w - bf2f(hi.w));
    ((ushort4*)wh)[i4] = hi;
    ((ushort4*)wl)[i4] = lo;
}

// ---------- h = nrm * (xn @ proj_w^T) + b via bf16x3 MFMA ----------
__global__ __launch_bounds__(256) void proj_mfma_k(const unsigned short* __restrict__ xh,
                                                   const unsigned short* __restrict__ xl,
                                                   const unsigned short* __restrict__ wh,
                                                   const unsigned short* __restrict__ wl,
                                                   const float* __restrict__ bias,
                                                   const float* __restrict__ nrm,
                                                   float* __restrict__ h) {
    int tid = threadIdx.x;
    int wave = tid >> 6, l = tid & 63;
    int m0 = blockIdx.y * 64 + wave * 16;
    int n0 = blockIdx.x * 64;
    int lr = l & 15;
    int kq = (l >> 4) * 8;
    const unsigned short* pah = xh + (size_t)(m0 + lr) * IN_FT + kq;
    const unsigned short* pal = xl + (size_t)(m0 + lr) * IN_FT + kq;
    f32x4 acc[4] = {};
    for (int k0 = 0; k0 < IN_FT; k0 += 32) {
        s16x8 ah = *(const s16x8*)(pah + k0);
        s16x8 al = *(const s16x8*)(pal + k0);
#pragma unroll
        for (int g = 0; g < 4; ++g) {
            const unsigned short* pbh = wh + (size_t)(n0 + g * 16 + lr) * IN_FT + kq + k0;
            const unsigned short* pbl = wl + (size_t)(n0 + g * 16 + lr) * IN_FT + kq + k0;
            s16x8 bh = *(const s16x8*)pbh;
            s16x8 bl = *(const s16x8*)pbl;
            acc[g] = __builtin_amdgcn_mfma_f32_16x16x32_bf16(ah, bh, acc[g], 0, 0, 0);
            acc[g] = __builtin_amdgcn_mfma_f32_16x16x32_bf16(ah, bl, acc[g], 0, 0, 0);
            acc[g] = __builtin_amdgcn_mfma_f32_16x16x32_bf16(al, bh, acc[g], 0, 0, 0);
        }
    }
#pragma unroll
    for (int g = 0; g < 4; ++g)
#pragma unroll
        for (int r = 0; r < 4; ++r) {
            int m = m0 + (l >> 4) * 4 + r;
            int n = n0 + g * 16 + lr;
            h[(size_t)m * OUT_FT + n] = nrm[m] * acc[g][r] + bias[n];
        }
}

// ---------- column build pass 1: per-(64-row chunk, e) bit counts ----------
__global__ __launch_bounds__(256) void count_cols_k(const unsigned* __restrict__ maskT,
                                                    int* __restrict__ cnt64) {
    __shared__ unsigned ch[512];               // [8 words][64 rows]
    int tid = threadIdx.x;
    int eb = blockIdx.x, chunk = blockIdx.y;   // chunk: 0..63 (64 rows each)
    int wbase = eb * 8, v0 = chunk * 64;
#pragma unroll
    for (int q = 0; q < 2; ++q) {
        int idx = tid + q * 256;               // 0..511
        int i = idx >> 6, r = idx & 63;
        ch[idx] = maskT[(size_t)(wbase + i) * N + v0 + r];
    }
    __syncthreads();
    int wl = tid >> 5, bp = tid & 31;
    int cnt = 0;
#pragma unroll
    for (int r = 0; r < 64; ++r) cnt += (ch[wl * 64 + r] >> bp) & 1;
    cnt64[chunk * N + eb * 256 + tid] = cnt;
}

// ---------- column build pass 2: fill at prefix offsets (same list order) ----------
__global__ __launch_bounds__(256) void fill_cols_k(const unsigned* __restrict__ maskT,
                                                   const int* __restrict__ cnt64,
                                                   const float* __restrict__ w1,
                                                   const float* __restrict__ Hmat,
                                                   int* __restrict__ elist,
                                                   float* __restrict__ eval_,
                                                   int* __restrict__ ecnt) {
    __shared__ unsigned ch[512];
    int tid = threadIdx.x;
    int eb = blockIdx.x, chunk = blockIdx.y;   // chunk: 0..63
    int e = eb * 256 + tid;
    int wbase = eb * 8, v0 = chunk * 64;
#pragma unroll
    for (int q = 0; q < 2; ++q) {
        int idx = tid + q * 256;
        int i = idx >> 6, r = idx & 63;
        ch[idx] = maskT[(size_t)(wbase + i) * N + v0 + r];
    }
    int pos = 0;
    for (int c = 0; c < chunk; ++c) pos += cnt64[c * N + e];  // coalesced, pipelined
    __syncthreads();
    int wl = tid >> 5;
    unsigned bit = 1u << (tid & 31);
#pragma unroll
    for (int r = 0; r < 64; ++r) {
        if (ch[wl * 64 + r] & bit) {
            if (pos < CAP) {
                size_t ofs = (size_t)(v0 + r) * N + e;
                elist[(size_t)e * CAP + pos] = v0 + r;
                eval_[(size_t)e * CAP + pos] = w1[ofs] * Hmat[ofs];
            }
            ++pos;
        }
    }
    if (chunk == 63) ecnt[e] = pos < CAP ? pos : CAP;
}

// ---------- dst[i,:] = (1/max(sum|val|,eps)) * sum val*src[list,:] ----------
__global__ __launch_bounds__(256) void spmm_k(const int* __restrict__ list,
                                              const float* __restrict__ val,
                                              const int* __restrict__ cnt,
                                              const float* __restrict__ src,
                                              float* __restrict__ dst) {
    int i = blockIdx.x;
    int f2 = threadIdx.x;
    int c = cnt[i];
    float ssum = 0.f;
    for (int t = 0; t < c; ++t) ssum += fabsf(val[(size_t)i * CAP + t]);
    float acc0 = 0.f, acc1 = 0.f;
    for (int t = 0; t < c; ++t) {
        int j = list[(size_t)i * CAP + t];
        float a = val[(size_t)i * CAP + t];
        float2 s = *(const float2*)&src[(size_t)j * OUT_FT + f2 * 2];
        acc0 += a * s.x;
        acc1 += a * s.y;
    }
    float sc = 1.0f / fmaxf(ssum, EPSN);
    float2 o = make_float2(acc0 * sc, acc1 * sc);
    *(float2*)&dst[(size_t)i * OUT_FT + f2 * 2] = o;
}

extern "C" void kernel_launch(void* const* d_in, const int* in_sizes, int n_in,
                              void* d_out, int out_size, void* d_ws, size_t ws_size,
                              hipStream_t stream) {
    const float* x      = (const float*)d_in[0];   // [4096,512]
    const float* Hmat   = (const float*)d_in[1];   // [4096,4096]
    const float* proj_w = (const float*)d_in[2];   // [512,512]
    const float* proj_b = (const float*)d_in[3];   // [512]
    const float* w1     = (const float*)d_in[4];   // [4096,4096]
    const float* w2     = (const float*)d_in[5];   // [4096,4096]
    float* out = (float*)d_out;

    char* ws = (char*)d_ws;   // ~59 MB total, NO aliasing
    unsigned short* xnh     = (unsigned short*)(ws + 0);         // 4 MB
    unsigned short* xnl     = (unsigned short*)(ws + 4194304);   // 4 MB
    unsigned*       cpack   = (unsigned*)(ws + 8388608);         // 12.58 MB [4096][768]
    int*            ccntg   = (int*)(ws + 20971520);             // 512 KB [4096][32]
    float*          h       = (float*)(ws + 21495808);           // 8 MB
    float*          h2      = (float*)(ws + 29884416);           // 8 MB
    unsigned short* whi     = (unsigned short*)(ws + 38273024);  // 512 KB
    unsigned short* wlo     = (unsigned short*)(ws + 38797312);  // 512 KB
    unsigned*       maskT   = (unsigned*)(ws + 39321600);        // 2 MB
    int*            cnt64   = (int*)(ws + 41418752);             // 1 MB [64][4096]
    int*            ecnt    = (int*)(ws + 42467328);             // 16 KB
    int*            rcnt    = (int*)(ws + 42483712);             // 16 KB
    float*          norminv = (float*)(ws + 42500096);           // 16 KB
    float*          nrm     = (float*)(ws + 42516480);           // 16 KB
    int*            fbflag  = (int*)(ws + 42532864);             // 16 KB
    int*            rlist   = (int*)(ws + 42549248);             // 4 MB
    float*          rval    = (float*)(ws + 46743552);           // 4 MB
    int*            elist   = (int*)(ws + 50937856);             // 4 MB
    float*          eval_   = (float*)(ws + 55132160);           // 4 MB -> ends ~59 MB

    // 1. norms + bf16 hi/lo of xn; NaN-fill cpack; zero fallback flags
    rownorm_k<<<N, 256, 0, stream>>>(x, xnh, xnl, norminv, nrm, fbflag, cpack);
    // 2. approx cos (bf16x1, 16 K-steps): upper-tri MFMA + mirror; packed slots
    cos_gemm_k<<<CNB * (CNB + 1) / 2, 256, 0, stream>>>(xnh, cpack, ccntg);
    // 3. top-k: 2 rows/block, 2 co-op waves per row (8192 waves total)
    topk_fast_k<<<N / 2, 256, 0, stream>>>(cpack, ccntg, x, norminv, maskT,
                                           w2, Hmat, rlist, rval, rcnt, fbflag);
    // 4. fallback rows: exact recompute + selection (overwrites row outputs)
    topk_fb_k<<<N, 256, 0, stream>>>(fbflag, x, norminv, maskT,
                                     w2, Hmat, rlist, rval, rcnt);
    // 5. h = nrm*(xn @ proj_w^T) + b
    cast_w_k<<<256, 256, 0, stream>>>(proj_w, whi, wlo);
    proj_mfma_k<<<dim3(OUT_FT / 64, N / 64), 256, 0, stream>>>(xnh, xnl, whi, wlo,
                                                               proj_b, nrm, h);
    // 6. column lists: count -> fill at prefix offsets (64-row chunks)
    count_cols_k<<<dim3(16, 64), 256, 0, stream>>>(maskT, cnt64);
    fill_cols_k<<<dim3(16, 64), 256, 0, stream>>>(maskT, cnt64, w1, Hmat, elist, eval_, ecnt);
    // 7. h2[e,:] = normalize . gather-sum over column lists
    spmm_k<<<N, 256, 0, stream>>>(elist, eval_, ecnt, h, h2);
    // 8. out[v,:] = normalize . gather-sum over row lists
    spmm_k<<<N, 256, 0, stream>>>(rlist, rval, rcnt, h2, out);
}

// Round 33
// 222.481 us; speedup vs baseline: 1.0722x; 1.0722x over previous
//
#include <hip/hip_runtime.h>
#include <hip/hip_bf16.h>
#include <math.h>

#define N 4096
#define IN_FT 512
#define OUT_FT 512
#define COS_THR 0.5f
#define COS_K 10
#define EPSN 1e-12f
#define CAP 256          // max stored nnz per row/col (actual ~10)
#define NW (N / 32)      // bitmask words per row
#define CAP_C 128        // window candidate slots (exact-fix path)
#define GAPWIN 1e-2f     // >= 2*delta'; bf16x1 delta 4e-3 + pack trunc 5e-4
#define CNB 32           // 128-blocks per side
#define T0 0.08f         // candidate threshold (guards make this safe)
#define SLOTS 24         // slots per (row, 128-col cell); P(overflow)~4e-6 total
#define NSLOT (32 * SLOTS)   // 768 slots per row = 12 per lane

typedef short s16x8 __attribute__((ext_vector_type(8)));
typedef float f32x4 __attribute__((ext_vector_type(4)));

__device__ __forceinline__ unsigned short f2bf(float f) {
    unsigned u = __float_as_uint(f);
    u += 0x7fff + ((u >> 16) & 1);          // RNE to bf16
    return (unsigned short)(u >> 16);
}
__device__ __forceinline__ float bf2f(unsigned short h) {
    return __uint_as_float(((unsigned)h) << 16);
}
__device__ __forceinline__ void gload_lds16(const void* g, void* l) {
    __builtin_amdgcn_global_load_lds(
        (const __attribute__((address_space(1))) void*)g,
        (__attribute__((address_space(3))) void*)l, 16, 0, 0);
}

// ---------- row-normalize: bf16 hi/lo of xn + norms; NaN-fill cpack row ----------
__global__ __launch_bounds__(256) void rownorm_k(const float* __restrict__ x,
                                                 unsigned short* __restrict__ xnh,
                                                 unsigned short* __restrict__ xnl,
                                                 float* __restrict__ norminv,
                                                 float* __restrict__ nrm,
                                                 int* __restrict__ fbflag,
                                                 unsigned* __restrict__ cpack) {
    int row = blockIdx.x;
    const float* xr = x + (size_t)row * IN_FT;
    // NaN-fill this row's packed slots (replaces the separate memset dispatch)
#pragma unroll
    for (int q = 0; q < 3; ++q)
        cpack[(size_t)row * NSLOT + threadIdx.x + q * 256] = 0xFFFFFFFFu;
    float s = 0.f;
    for (int j = threadIdx.x; j < IN_FT; j += 256) { float v = xr[j]; s += v * v; }
    __shared__ float red[256];
    red[threadIdx.x] = s; __syncthreads();
    for (int off = 128; off > 0; off >>= 1) {
        if (threadIdx.x < off) red[threadIdx.x] += red[threadIdx.x + off];
        __syncthreads();
    }
    float nr = fmaxf(sqrtf(red[0]), 1e-12f);
    float inv = 1.0f / nr;
    if (threadIdx.x == 0) { norminv[row] = inv; nrm[row] = nr; fbflag[row] = 0; }
    for (int j = threadIdx.x; j < IN_FT; j += 256) {
        float v = xr[j] * inv;                 // same op the exact paths replay
        unsigned short hi = f2bf(v);
        unsigned short lo = f2bf(v - bf2f(hi));
        xnh[(size_t)row * IN_FT + j] = hi;
        xnl[(size_t)row * IN_FT + j] = lo;
    }
}

// ---------- approx cos: bf16x1 MFMA, upper-tri + mirror; PACKED slot emission ----------
__global__ __launch_bounds__(256) void cos_gemm_k(const unsigned short* __restrict__ xh,
                                                  unsigned* __restrict__ cpack,
                                                  int* __restrict__ ccntg) {
    __shared__ __align__(16) unsigned short As[2][128 * 32];
    __shared__ __align__(16) unsigned short Bs[2][128 * 32];
    __shared__ int cntU[128], cntM[128];
    int bid = blockIdx.x;                      // 0 .. 527
    int t = (bid & 7) * 66 + (bid >> 3);       // XCD-chunked bijection
    int by = 0;
    while (t >= CNB - by) { t -= CNB - by; ++by; }
    int bx = by + t;                           // by <= bx
    int tid = threadIdx.x;
    int wave = tid >> 6, l = tid & 63;
    int bi = by * 128, bj = bx * 128;
    int wm = wave >> 1, wn = wave & 1;
    int lm0 = wm * 64, ln0 = wn * 64;
    int lr4 = l >> 2;
    int lc4s = (((l & 3) ^ ((l >> 3) & 3)) * 8);   // swizzled SOURCE chunk
    int lr = l & 15, lg = l >> 4;
    int kqs = (((l >> 4) ^ ((l >> 1) & 3)) * 8);   // swizzled read chunk
    f32x4 acc[4][4] = {};
    int buf = 0;
#pragma unroll
    for (int q = 0; q < 2; ++q) {
        int r0 = (wave + q * 4) * 16;
        gload_lds16(xh + (size_t)(bi + r0 + lr4) * IN_FT + lc4s, &As[0][r0 * 32]);
        gload_lds16(xh + (size_t)(bj + r0 + lr4) * IN_FT + lc4s, &Bs[0][r0 * 32]);
    }
    asm volatile("s_waitcnt vmcnt(0)" ::: "memory");
    __syncthreads();
    for (int kt = 0; kt < 16; ++kt) {
        if (kt + 1 < 16) {
            int kc = (kt + 1) * 32;
#pragma unroll
            for (int q = 0; q < 2; ++q) {
                int r0 = (wave + q * 4) * 16;
                gload_lds16(xh + (size_t)(bi + r0 + lr4) * IN_FT + kc + lc4s,
                            &As[buf ^ 1][r0 * 32]);
                gload_lds16(xh + (size_t)(bj + r0 + lr4) * IN_FT + kc + lc4s,
                            &Bs[buf ^ 1][r0 * 32]);
            }
        }
        s16x8 a[4], b[4];
#pragma unroll
        for (int mi = 0; mi < 4; ++mi)
            a[mi] = *(const s16x8*)&As[buf][(lm0 + mi * 16 + lr) * 32 + kqs];
#pragma unroll
        for (int ni = 0; ni < 4; ++ni)
            b[ni] = *(const s16x8*)&Bs[buf][(ln0 + ni * 16 + lr) * 32 + kqs];
#pragma unroll
        for (int mi = 0; mi < 4; ++mi)
#pragma unroll
            for (int ni = 0; ni < 4; ++ni)
                acc[mi][ni] = __builtin_amdgcn_mfma_f32_16x16x32_bf16(a[mi], b[ni], acc[mi][ni], 0, 0, 0);
        asm volatile("s_waitcnt vmcnt(0)" ::: "memory");
        __syncthreads();
        buf ^= 1;
    }
    // ---- packed slot emission epilogue ----
    if (tid < 128) { cntU[tid] = 0; cntM[tid] = 0; }
    __syncthreads();
#pragma unroll
    for (int mi = 0; mi < 4; ++mi)
#pragma unroll
        for (int r = 0; r < 4; ++r) {
            int rl = lm0 + mi * 16 + lg * 4 + r;
#pragma unroll
            for (int ni = 0; ni < 4; ++ni) {
                float val = acc[mi][ni][r];
                if (val > T0) {
                    int p = atomicAdd(&cntU[rl], 1);
                    if (p < SLOTS) {
                        int n = bj + ln0 + ni * 16 + lr;
                        size_t base = ((size_t)(bi + rl) * 32 + bx) * SLOTS + p;
                        cpack[base] = (__float_as_uint(val) & 0xFFFFF000u) | (unsigned)n;
                    }
                }
            }
        }
    if (bx != by) {
#pragma unroll
        for (int ni = 0; ni < 4; ++ni) {
            int rl2 = ln0 + ni * 16 + lr;
#pragma unroll
            for (int mi = 0; mi < 4; ++mi)
#pragma unroll
                for (int r = 0; r < 4; ++r) {
                    float val = acc[mi][ni][r];
                    if (val > T0) {
                        int p = atomicAdd(&cntM[rl2], 1);
                        if (p < SLOTS) {
                            int col = bi + lm0 + mi * 16 + lg * 4 + r;
                            size_t base = ((size_t)(bj + rl2) * 32 + by) * SLOTS + p;
                            cpack[base] = (__float_as_uint(val) & 0xFFFFF000u) | (unsigned)col;
                        }
                    }
                }
        }
    }
    __syncthreads();
    if (tid < 128) {
        ccntg[(size_t)(bi + tid) * 32 + bx] = cntU[tid];
        if (bx != by) ccntg[(size_t)(bj + tid) * 32 + by] = cntM[tid];
    }
}

// ---------- top-k over packed slots: 4 independent rows per block (r29 version) ----------
__global__ __launch_bounds__(256) void topk_fast_k(const unsigned* __restrict__ cpack,
                                                   const int* __restrict__ ccntg,
                                                   const float* __restrict__ x,
                                                   const float* __restrict__ norminv,
                                                   unsigned* __restrict__ maskT,
                                                   const float* __restrict__ w2,
                                                   const float* __restrict__ Hmat,
                                                   int* __restrict__ rlist,
                                                   float* __restrict__ rval,
                                                   int* __restrict__ rcnt,
                                                   int* __restrict__ fbflag) {
    int wid = threadIdx.x >> 6, lane = threadIdx.x & 63;
    int row = blockIdx.x * 4 + wid;
    __shared__ int   cjj_s[4][CAP_C];
    __shared__ float exv_s[4][CAP_C];
    __shared__ unsigned char selw_s[4][CAP_C];
    __shared__ unsigned lmask_s[4][NW];
    __shared__ float xs_s[4][IN_FT];
    int*            cjj  = cjj_s[wid];
    float*          exv  = exv_s[wid];
    unsigned char*  selw = selw_s[wid];
    unsigned*       lmask = lmask_s[wid];
    float*          xs   = xs_s[wid];
    // --- guards from cell counts (shfl reduce) ---
    int cc = (lane < 32) ? ccntg[(size_t)row * 32 + lane] : 0;
    int sum = cc, mx = cc;
#pragma unroll
    for (int off = 32; off > 0; off >>= 1) {
        sum += __shfl_xor(sum, off);
        int m2 = __shfl_xor(mx, off);
        mx = m2 > mx ? m2 : mx;
    }
    if (mx > SLOTS || sum < COS_K) { if (lane == 0) fbflag[row] = 1; return; }
    // --- load 12 packed slots/lane (coalesced; NaN -> inert) ---
    const unsigned* cpr = cpack + (size_t)row * NSLOT;
    float cv[12]; int ci[12];
#pragma unroll
    for (int i = 0; i < 12; ++i) {
        unsigned u = cpr[lane + i * 64];
        float v = __uint_as_float(u & 0xFFFFF000u);
        bool ok = (v == v);
        cv[i] = ok ? v : -INFINITY;
        ci[i] = ok ? (int)(u & 0xFFFu) : 0x7fffffff;
    }
    // --- top-10 on approx, (value desc, index asc) order; win uniform ---
    int winr[10];
    float v10 = 0.f;
    unsigned exm = 0;
    for (int t = 0; t < COS_K; ++t) {
        float best = -INFINITY; int bidx = 0x7fffffff;
#pragma unroll
        for (int i = 0; i < 12; ++i)
            if (!((exm >> i) & 1) &&
                (cv[i] > best || (cv[i] == best && ci[i] < bidx))) { best = cv[i]; bidx = ci[i]; }
#pragma unroll
        for (int off = 32; off > 0; off >>= 1) {
            float v2 = __shfl_xor(best, off);
            int   i2 = __shfl_xor(bidx, off);
            if (v2 > best || (v2 == best && i2 < bidx)) { best = v2; bidx = i2; }
        }
#pragma unroll
        for (int i = 0; i < 12; ++i)            // j unique -> owner marks
            if (ci[i] == bidx) exm |= 1u << i;
        winr[t] = bidx;                         // wave-uniform
        if (t == COS_K - 1) v10 = best;
    }
    if (v10 - GAPWIN <= T0) { if (lane == 0) fbflag[row] = 1; return; }
    // --- window membership + provisional flags ---
    unsigned iswm = 0; int wc = 0;
    unsigned char flag[12];
#pragma unroll
    for (int i = 0; i < 12; ++i) {
        bool w = (cv[i] > v10 - GAPWIN) || (fabsf(cv[i] - COS_THR) < GAPWIN);
        if (w) { iswm |= 1u << i; ++wc; }
        bool iw = false;
#pragma unroll
        for (int t = 0; t < COS_K; ++t) iw |= (winr[t] == ci[i]);
        flag[i] = (cv[i] > COS_THR || iw) ? 1 : 0;
    }
    int scan = wc;
#pragma unroll
    for (int off = 1; off < 64; off <<= 1) {
        int nv = __shfl_up(scan, off);
        if (lane >= off) scan += nv;
    }
    int Mw = __shfl(scan, 63);
    if (Mw > CAP_C) { if (lane == 0) fbflag[row] = 1; return; }
    if (Mw > COS_K) {                           // exact fix of the window
        {
            const float4* xr4 = (const float4*)(x + (size_t)row * IN_FT);
            ((float4*)xs)[lane] = xr4[lane];
            ((float4*)xs)[lane + 64] = xr4[lane + 64];
        }
        int base = scan - wc;
        int mypos[12];
        {
            int pos = base;
#pragma unroll
            for (int i = 0; i < 12; ++i) {
                if ((iswm >> i) & 1) { cjj[pos] = ci[i]; mypos[i] = pos; ++pos; }
                else mypos[i] = -1;
            }
        }
        float invr = norminv[row];
        int grp = lane >> 4;                    // 0..3 member group
        int q = lane & 15;                      // k-segment within member
        for (int mb = 0; mb < Mw; mb += 4) {    // 4 members per pass
            int m = mb + grp;
            float part = 0.f;
            int j = (m < Mw) ? cjj[m] : cjj[0];
            float invj_ = norminv[j];
            const float4* xj4 = (const float4*)(x + (size_t)j * IN_FT);
            int kb = q * 32;
            float4 e0 = xj4[q * 8 + 0], e1 = xj4[q * 8 + 1];
            float4 e2 = xj4[q * 8 + 2], e3 = xj4[q * 8 + 3];
            float4 e4 = xj4[q * 8 + 4], e5 = xj4[q * 8 + 5];
            float4 e6 = xj4[q * 8 + 6], e7 = xj4[q * 8 + 7];
            const float4* f4s[8] = {&e0, &e1, &e2, &e3, &e4, &e5, &e6, &e7};
#pragma unroll
            for (int s = 0; s < 8; ++s) {
                float4 e = *f4s[s];
                part = fmaf(xs[kb + s * 4 + 0] * invr, e.x * invj_, part);
                part = fmaf(xs[kb + s * 4 + 1] * invr, e.y * invj_, part);
                part = fmaf(xs[kb + s * 4 + 2] * invr, e.z * invj_, part);
                part = fmaf(xs[kb + s * 4 + 3] * invr, e.w * invj_, part);
            }
#pragma unroll
            for (int off = 1; off < 16; off <<= 1)
                part += __shfl_xor(part, off);
            if (q == 0 && m < Mw) exv[m] = part;
        }
        for (int w = lane; w < Mw; w += 64) {   // rank, identical comparator
            float vv = exv[w]; int j = cjj[w];
            int rank = 0;
            for (int m2 = 0; m2 < Mw; ++m2) {
                float v2 = exv[m2]; int j2 = cjj[m2];
                if (v2 > vv || (v2 == vv && j2 < j)) ++rank;
            }
            selw[w] = (rank < COS_K) ? 1 : 0;
        }
#pragma unroll
        for (int i = 0; i < 12; ++i)
            if (mypos[i] >= 0)
                flag[i] = ((exv[mypos[i]] > COS_THR) || selw[mypos[i]]) ? 1 : 0;
    }
    // --- build row bitmask (intra-wave LDS ops program-ordered) ---
    lmask[lane] = 0; lmask[lane + 64] = 0;
#pragma unroll
    for (int i = 0; i < 12; ++i)
        if (flag[i]) atomicOr(&lmask[ci[i] >> 5], 1u << (ci[i] & 31));
    unsigned w0 = lmask[lane], w1 = lmask[lane + 64];
    maskT[(size_t)lane * N + row] = w0;
    maskT[(size_t)(lane + 64) * N + row] = w1;
    // --- row list (ascending j) ---
    int c0 = __popc(w0), c1 = __popc(w1);
    int s0 = c0, s1 = c1;
#pragma unroll
    for (int off = 1; off < 64; off <<= 1) {
        int n0 = __shfl_up(s0, off);
        int n1 = __shfl_up(s1, off);
        if (lane >= off) { s0 += n0; s1 += n1; }
    }
    int tot0 = __shfl(s0, 63), tot1 = __shfl(s1, 63);
    int b0 = s0 - c0, b1 = tot0 + s1 - c1;
    {
        unsigned m = w0; int pos = b0;
        while (m) {
            int b = __builtin_ctz(m); m &= m - 1;
            int j = lane * 32 + b;
            if (pos < CAP) {
                size_t ofs = (size_t)row * N + j;
                rlist[(size_t)row * CAP + pos] = j;
                rval[(size_t)row * CAP + pos] = w2[ofs] * Hmat[ofs];
            }
            ++pos;
        }
        m = w1; pos = b1;
        while (m) {
            int b = __builtin_ctz(m); m &= m - 1;
            int j = (lane + 64) * 32 + b;
            if (pos < CAP) {
                size_t ofs = (size_t)row * N + j;
                rlist[(size_t)row * CAP + pos] = j;
                rval[(size_t)row * CAP + pos] = w2[ofs] * Hmat[ofs];
            }
            ++pos;
        }
    }
    if (lane == 0) {
        int tot = tot0 + tot1;
        rcnt[row] = tot < CAP ? tot : CAP;
    }
}

// ---------- fallback: EXACT row recompute + selection (guarded, rare) ----------
__global__ __launch_bounds__(256) void topk_fb_k(const int* __restrict__ fbflag,
                                                 const float* __restrict__ x,
                                                 const float* __restrict__ norminv,
                                                 unsigned* __restrict__ maskT,
                                                 const float* __restrict__ w2,
                                                 const float* __restrict__ Hmat,
                                                 int* __restrict__ rlist,
                                                 float* __restrict__ rval,
                                                 int* __restrict__ rcnt) {
    int row = blockIdx.x;
    if (!fbflag[row]) return;
    int tid = threadIdx.x;
    int lane = tid & 63, wid = tid >> 6;
    __shared__ float xrow[IN_FT];
    __shared__ float wv[4][10];
    __shared__ int   wi[4][10];
    __shared__ int   win[10];
    __shared__ int   wtot[4];
    const float* xr = x + (size_t)row * IN_FT;
    xrow[tid] = xr[tid]; xrow[tid + 256] = xr[tid + 256];
    __syncthreads();
    float invr = norminv[row];
    float v[16];
    const float4* xjp[16];
    float invj[16];
#pragma unroll
    for (int c = 0; c < 16; ++c) {
        int j = tid * 16 + c;
        xjp[c] = (const float4*)(x + (size_t)j * IN_FT);
        invj[c] = norminv[j];
        v[c] = 0.f;
    }
    for (int k4 = 0; k4 < IN_FT / 4; ++k4) {
        float xv0 = xrow[k4 * 4 + 0] * invr;
        float xv1 = xrow[k4 * 4 + 1] * invr;
        float xv2 = xrow[k4 * 4 + 2] * invr;
        float xv3 = xrow[k4 * 4 + 3] * invr;
#pragma unroll
        for (int c = 0; c < 16; ++c) {
            float4 e = xjp[c][k4];
            v[c] = fmaf(xv0, e.x * invj[c], v[c]);
            v[c] = fmaf(xv1, e.y * invj[c], v[c]);
            v[c] = fmaf(xv2, e.z * invj[c], v[c]);
            v[c] = fmaf(xv3, e.w * invj[c], v[c]);
        }
    }
    unsigned fl = 0;
#pragma unroll
    for (int c = 0; c < 16; ++c)
        if (v[c] > COS_THR) fl |= 1u << c;
    unsigned exm = 0;
#pragma unroll
    for (int t = 0; t < COS_K; ++t) {
        float best = -INFINITY; int bidx = 0x7fffffff;
#pragma unroll
        for (int c = 0; c < 16; ++c)
            if (!((exm >> c) & 1) && v[c] > best) { best = v[c]; bidx = tid * 16 + c; }
#pragma unroll
        for (int off = 32; off > 0; off >>= 1) {
            float v2 = __shfl_xor(best, off);
            int   i2 = __shfl_xor(bidx, off);
            if (v2 > best || (v2 == best && i2 < bidx)) { best = v2; bidx = i2; }
        }
        if ((bidx >> 4) == tid) exm |= 1u << (bidx & 15);
        if (lane == t) { wv[wid][t] = best; wi[wid][t] = bidx; }
    }
    __syncthreads();
    if (wid == 0) {
        float mv = -INFINITY; int mi = 0x7fffffff;
        if (lane < 40) { int g = lane / 10, s = lane - g * 10; mv = wv[g][s]; mi = wi[g][s]; }
        for (int t = 0; t < COS_K; ++t) {
            float best = mv; int bidx = mi;
#pragma unroll
            for (int off = 32; off > 0; off >>= 1) {
                float v2 = __shfl_xor(best, off);
                int   i2 = __shfl_xor(bidx, off);
                if (v2 > best || (v2 == best && i2 < bidx)) { best = v2; bidx = i2; }
            }
            if (mi == bidx) mv = -INFINITY;
            if (lane == 0) win[t] = bidx;
        }
    }
    __syncthreads();
#pragma unroll
    for (int t = 0; t < COS_K; ++t) {
        int wj = win[t];
        if ((wj >> 4) == tid) fl |= 1u << (wj & 15);
    }
    unsigned flp = __shfl_xor(fl, 1);
    if (!(tid & 1))
        maskT[(size_t)(tid >> 1) * N + row] = (fl & 0xffffu) | (flp << 16);
    int cnt = __popc(fl);
    int scan = cnt;
#pragma unroll
    for (int off = 1; off < 64; off <<= 1) {
        int nv = __shfl_up(scan, off);
        if (lane >= off) scan += nv;
    }
    if (lane == 63) wtot[wid] = scan;
    __syncthreads();
    int base = scan - cnt;
    for (int w = 0; w < wid; ++w) base += wtot[w];
    unsigned m = fl;
    int pos = base;
    while (m) {
        int c = __builtin_ctz(m); m &= m - 1;
        int j = tid * 16 + c;
        if (pos < CAP) {
            size_t ofs = (size_t)row * N + j;
            rlist[(size_t)row * CAP + pos] = j;
            rval[(size_t)row * CAP + pos] = w2[ofs] * Hmat[ofs];
        }
        ++pos;
    }
    if (tid == 0) {
        int tot = wtot[0] + wtot[1] + wtot[2] + wtot[3];
        rcnt[row] = tot < CAP ? tot : CAP;
    }
}

// ---------- split proj_w into bf16 (hi, lo) ----------
__global__ __launch_bounds__(256) void cast_w_k(const float* __restrict__ w,
                                                unsigned short* __restrict__ wh,
                                                unsigned short* __restrict__ wl) {
    int i4 = blockIdx.x * 256 + threadIdx.x;   // 65536 float4s
    float4 f = ((const float4*)w)[i4];
    ushort4 hi, lo;
    hi.x = f2bf(f.x); lo.x = f2bf(f.x - bf2f(hi.x));
    hi.y = f2bf(f.y); lo.y = f2bf(f.y - bf2f(hi.y));
    hi.z = f2bf(f.z); lo.z = f2bf(f.z - bf2f(hi.z));
    hi.w = f2bf(f.w); lo.w = f2bf(f.w - bf2f(hi.w));
    ((ushort4*)wh)[i4] = hi;
    ((ushort4*)wl)[i4] = lo;
}

// ---------- h = nrm * (xn @ proj_w^T) + b via bf16x3 MFMA ----------
__global__ __launch_bounds__(256) void proj_mfma_k(const unsigned short* __restrict__ xh,
                                                   const unsigned short* __restrict__ xl,
                                                   const unsigned short* __restrict__ wh,
                                                   const unsigned short* __restrict__ wl,
                                                   const float* __restrict__ bias,
                                                   const float* __restrict__ nrm,
                                                   float* __restrict__ h) {
    int tid = threadIdx.x;
    int wave = tid >> 6, l = tid & 63;
    int m0 = blockIdx.y * 64 + wave * 16;
    int n0 = blockIdx.x * 64;
    int lr = l & 15;
    int kq = (l >> 4) * 8;
    const unsigned short* pah = xh + (size_t)(m0 + lr) * IN_FT + kq;
    const unsigned short* pal = xl + (size_t)(m0 + lr) * IN_FT + kq;
    f32x4 acc[4] = {};
    for (int k0 = 0; k0 < IN_FT; k0 += 32) {
        s16x8 ah = *(const s16x8*)(pah + k0);
        s16x8 al = *(const s16x8*)(pal + k0);
#pragma unroll
        for (int g = 0; g < 4; ++g) {
            const unsigned short* pbh = wh + (size_t)(n0 + g * 16 + lr) * IN_FT + kq + k0;
            const unsigned short* pbl = wl + (size_t)(n0 + g * 16 + lr) * IN_FT + kq + k0;
            s16x8 bh = *(const s16x8*)pbh;
            s16x8 bl = *(const s16x8*)pbl;
            acc[g] = __builtin_amdgcn_mfma_f32_16x16x32_bf16(ah, bh, acc[g], 0, 0, 0);
            acc[g] = __builtin_amdgcn_mfma_f32_16x16x32_bf16(ah, bl, acc[g], 0, 0, 0);
            acc[g] = __builtin_amdgcn_mfma_f32_16x16x32_bf16(al, bh, acc[g], 0, 0, 0);
        }
    }
#pragma unroll
    for (int g = 0; g < 4; ++g)
#pragma unroll
        for (int r = 0; r < 4; ++r) {
            int m = m0 + (l >> 4) * 4 + r;
            int n = n0 + g * 16 + lr;
            h[(size_t)m * OUT_FT + n] = nrm[m] * acc[g][r] + bias[n];
        }
}

// ---------- column build pass 1: per-(64-row chunk, e) bit counts ----------
__global__ __launch_bounds__(256) void count_cols_k(const unsigned* __restrict__ maskT,
                                                    int* __restrict__ cnt64) {
    __shared__ unsigned ch[512];               // [8 words][64 rows]
    int tid = threadIdx.x;
    int eb = blockIdx.x, chunk = blockIdx.y;   // chunk: 0..63 (64 rows each)
    int wbase = eb * 8, v0 = chunk * 64;
#pragma unroll
    for (int q = 0; q < 2; ++q) {
        int idx = tid + q * 256;               // 0..511
        int i = idx >> 6, r = idx & 63;
        ch[idx] = maskT[(size_t)(wbase + i) * N + v0 + r];
    }
    __syncthreads();
    int wl = tid >> 5, bp = tid & 31;
    int cnt = 0;
#pragma unroll
    for (int r = 0; r < 64; ++r) cnt += (ch[wl * 64 + r] >> bp) & 1;
    cnt64[chunk * N + eb * 256 + tid] = cnt;
}

// ---------- column build pass 2: fill at prefix offsets (same list order) ----------
__global__ __launch_bounds__(256) void fill_cols_k(const unsigned* __restrict__ maskT,
                                                   const int* __restrict__ cnt64,
                                                   const float* __restrict__ w1,
                                                   const float* __restrict__ Hmat,
                                                   int* __restrict__ elist,
                                                   float* __restrict__ eval_,
                                                   int* __restrict__ ecnt) {
    __shared__ unsigned ch[512];
    int tid = threadIdx.x;
    int eb = blockIdx.x, chunk = blockIdx.y;   // chunk: 0..63
    int e = eb * 256 + tid;
    int wbase = eb * 8, v0 = chunk * 64;
#pragma unroll
    for (int q = 0; q < 2; ++q) {
        int idx = tid + q * 256;
        int i = idx >> 6, r = idx & 63;
        ch[idx] = maskT[(size_t)(wbase + i) * N + v0 + r];
    }
    int pos = 0;
    for (int c = 0; c < chunk; ++c) pos += cnt64[c * N + e];  // coalesced, pipelined
    __syncthreads();
    int wl = tid >> 5;
    unsigned bit = 1u << (tid & 31);
#pragma unroll
    for (int r = 0; r < 64; ++r) {
        if (ch[wl * 64 + r] & bit) {
            if (pos < CAP) {
                size_t ofs = (size_t)(v0 + r) * N + e;
                elist[(size_t)e * CAP + pos] = v0 + r;
                eval_[(size_t)e * CAP + pos] = w1[ofs] * Hmat[ofs];
            }
            ++pos;
        }
    }
    if (chunk == 63) ecnt[e] = pos < CAP ? pos : CAP;
}

// ---------- dst[i,:] = (1/max(sum|val|,eps)) * sum val*src[list,:] ----------
__global__ __launch_bounds__(256) void spmm_k(const int* __restrict__ list,
                                              const float* __restrict__ val,
                                              const int* __restrict__ cnt,
                                              const float* __restrict__ src,
                                              float* __restrict__ dst) {
    int i = blockIdx.x;
    int f2 = threadIdx.x;
    int c = cnt[i];
    float ssum = 0.f;
    for (int t = 0; t < c; ++t) ssum += fabsf(val[(size_t)i * CAP + t]);
    float acc0 = 0.f, acc1 = 0.f;
    for (int t = 0; t < c; ++t) {
        int j = list[(size_t)i * CAP + t];
        float a = val[(size_t)i * CAP + t];
        float2 s = *(const float2*)&src[(size_t)j * OUT_FT + f2 * 2];
        acc0 += a * s.x;
        acc1 += a * s.y;
    }
    float sc = 1.0f / fmaxf(ssum, EPSN);
    float2 o = make_float2(acc0 * sc, acc1 * sc);
    *(float2*)&dst[(size_t)i * OUT_FT + f2 * 2] = o;
}

extern "C" void kernel_launch(void* const* d_in, const int* in_sizes, int n_in,
                              void* d_out, int out_size, void* d_ws, size_t ws_size,
                              hipStream_t stream) {
    const float* x      = (const float*)d_in[0];   // [4096,512]
    const float* Hmat   = (const float*)d_in[1];   // [4096,4096]
    const float* proj_w = (const float*)d_in[2];   // [512,512]
    const float* proj_b = (const float*)d_in[3];   // [512]
    const float* w1     = (const float*)d_in[4];   // [4096,4096]
    const float* w2     = (const float*)d_in[5];   // [4096,4096]
    float* out = (float*)d_out;

    char* ws = (char*)d_ws;   // ~59 MB total, NO aliasing
    unsigned short* xnh     = (unsigned short*)(ws + 0);         // 4 MB
    unsigned short* xnl     = (unsigned short*)(ws + 4194304);   // 4 MB
    unsigned*       cpack   = (unsigned*)(ws + 8388608);         // 12.58 MB [4096][768]
    int*            ccntg   = (int*)(ws + 20971520);             // 512 KB [4096][32]
    float*          h       = (float*)(ws + 21495808);           // 8 MB
    float*          h2      = (float*)(ws + 29884416);           // 8 MB
    unsigned short* whi     = (unsigned short*)(ws + 38273024);  // 512 KB
    unsigned short* wlo     = (unsigned short*)(ws + 38797312);  // 512 KB
    unsigned*       maskT   = (unsigned*)(ws + 39321600);        // 2 MB
    int*            cnt64   = (int*)(ws + 41418752);             // 1 MB [64][4096]
    int*            ecnt    = (int*)(ws + 42467328);             // 16 KB
    int*            rcnt    = (int*)(ws + 42483712);             // 16 KB
    float*          norminv = (float*)(ws + 42500096);           // 16 KB
    float*          nrm     = (float*)(ws + 42516480);           // 16 KB
    int*            fbflag  = (int*)(ws + 42532864);             // 16 KB
    int*            rlist   = (int*)(ws + 42549248);             // 4 MB
    float*          rval    = (float*)(ws + 46743552);           // 4 MB
    int*            elist   = (int*)(ws + 50937856);             // 4 MB
    float*          eval_   = (float*)(ws + 55132160);           // 4 MB -> ends ~59 MB

    // 1. norms + bf16 hi/lo of xn; NaN-fill cpack; zero fallback flags
    rownorm_k<<<N, 256, 0, stream>>>(x, xnh, xnl, norminv, nrm, fbflag, cpack);
    // 2. approx cos (bf16x1, 16 K-steps): upper-tri MFMA + mirror; packed slots
    cos_gemm_k<<<CNB * (CNB + 1) / 2, 256, 0, stream>>>(xnh, cpack, ccntg);
    // 3. top-k: 4 independent rows per block (r29 version)
    topk_fast_k<<<N / 4, 256, 0, stream>>>(cpack, ccntg, x, norminv, maskT,
                                           w2, Hmat, rlist, rval, rcnt, fbflag);
    // 4. fallback rows: exact recompute + selection (overwrites row outputs)
    topk_fb_k<<<N, 256, 0, stream>>>(fbflag, x, norminv, maskT,
                                     w2, Hmat, rlist, rval, rcnt);
    // 5. h = nrm*(xn @ proj_w^T) + b
    cast_w_k<<<256, 256, 0, stream>>>(proj_w, whi, wlo);
    proj_mfma_k<<<dim3(OUT_FT / 64, N / 64), 256, 0, stream>>>(xnh, xnl, whi, wlo,
                                                               proj_b, nrm, h);
    // 6. column lists: count -> fill at prefix offsets (64-row chunks)
    count_cols_k<<<dim3(16, 64), 256, 0, stream>>>(maskT, cnt64);
    fill_cols_k<<<dim3(16, 64), 256, 0, stream>>>(maskT, cnt64, w1, Hmat, elist, eval_, ecnt);
    // 7. h2[e,:] = normalize . gather-sum over column lists
    spmm_k<<<N, 256, 0, stream>>>(elist, eval_, ecnt, h, h2);
    // 8. out[v,:] = normalize . gather-sum over row lists
    spmm_k<<<N, 256, 0, stream>>>(rlist, rval, rcnt, h2, out);
}